// Round 15
// baseline (451.419 us; speedup 1.0000x reference)
//
#include <hip/hip_runtime.h>
#include <float.h>
#include <stdint.h>

#define N_TOK 32768
#define N_E   8192
#define EDIM  256
#define MU_W  0.25f
#define NSPLIT 4
#define NRANGE 2048
#define BMr 64                /* block rows (tokens) */
#define MARGIN_F 4096.0f      /* scaled units (2^25): 1.2e-4 d >= ref-ulp + 2*quantum + 8-sigma noise */
#define OFFSETF (-0x1p21f)    /* makes every score negative -> raw-bit u32 max-ordering */
#define XSCALE 512.0f         /* 2^9 */
#define ESCALE -131072.0f     /* -2^17 ; product sums to -dot*2^26 = -2dot*2^25 */

typedef _Float16 f16;
typedef _Float16 f16x8 __attribute__((ext_vector_type(8)));
typedef _Float16 f16x4 __attribute__((ext_vector_type(4)));
typedef float f32x4 __attribute__((ext_vector_type(4)));
typedef unsigned int u32;
typedef unsigned long long u64;

// ws layout (bytes)
#define WS_EMB16   0
#define WS_SX      4194304
#define WS_SE      4325376
#define WS_SE25    4358144
#define WS_CAND    4390912
#define WS_PART    6488064
#define WS_RCNT    6619136
#define WS_RLIST   6619392
#define WS_RBEST   6750464   /* 32768 x u64 */

__device__ inline u32 umax_(u32 a, u32 b) { return a > b ? a : b; }
__device__ inline u32 umin_(u32 a, u32 b) { return a < b ? a : b; }

__device__ inline u32 med3u(u32 a, u32 b, u32 c) {
  u32 r;
  asm("v_med3_u32 %0, %1, %2, %3" : "=v"(r) : "v"(a), "v"(b), "v"(c));
  return r;
}

// sorted top-4 insert, DESCENDING u32 (a>=b>=c>=d; larger u32 = more-negative float = better)
__device__ inline void ins4max(u32 v, u32& a, u32& b, u32& c, u32& d) {
  u32 na = umax_(a, v);
  u32 nb = med3u(a, b, v);
  u32 nc = med3u(b, c, v);
  u32 nd = med3u(c, d, v);
  a = na; b = nb; c = nc; d = nd;
}

// ---------------- fused prepass: rownorms (exact tree) + fragment-linear scaled f16 + se*2^25 + rcnt=0 ----------------
// e16 layout: [colblock=j>>4][kslice=k>>3][col16=j&15] x 16B  (8192 B per 16-col block)
__global__ __launch_bounds__(256) void conv_fused(const float* __restrict__ emb,
                                                  const float* __restrict__ x,
                                                  char* __restrict__ dst16,
                                                  float* __restrict__ se,
                                                  float* __restrict__ se25,
                                                  float* __restrict__ sx,
                                                  u32* __restrict__ rcnt) {
  if (blockIdx.x == 0 && threadIdx.x == 0) rcnt[0] = 0u;
  int wave = threadIdx.x >> 6;
  int lane = threadIdx.x & 63;
  int row = blockIdx.x * 4 + wave;
  if (row < N_E) {
    const float4 v = *(const float4*)(emb + (size_t)row * EDIM + lane * 4);
    float s = (v.x * v.x + v.y * v.y) + (v.z * v.z + v.w * v.w);
#pragma unroll
    for (int off = 32; off >= 1; off >>= 1) s += __shfl_xor(s, off);
    if (lane == 0) { se[row] = s; se25[row] = s * 0x1p25f; }
    f16x4 h;
    h[0] = (f16)(v.x * ESCALE); h[1] = (f16)(v.y * ESCALE);
    h[2] = (f16)(v.z * ESCALE); h[3] = (f16)(v.w * ESCALE);
    *(f16x4*)(dst16 + (size_t)(row >> 4) * 8192 + (lane >> 1) * 256 +
              (row & 15) * 16 + (lane & 1) * 8) = h;
  } else {
    int xr = row - N_E;
    const float4 v = *(const float4*)(x + (size_t)xr * EDIM + lane * 4);
    float s = (v.x * v.x + v.y * v.y) + (v.z * v.z + v.w * v.w);
#pragma unroll
    for (int off = 32; off >= 1; off >>= 1) s += __shfl_xor(s, off);
    if (lane == 0) sx[xr] = s;
  }
}

// ---------------- stage-1: fp16 MFMA GEMM; A in LDS (staged once), B direct global->VGPR, no K-loop barriers ----------------
// grid 2048: split = bid&3, bm = (bid>>2)*64. 256 threads = 4 waves (wn), wave tile 64x64.
// amdgpu_waves_per_eu(2,2): pin regalloc to the 2-waves/EU budget (256 VGPR) -> no spill of the ~200-reg live state.
__global__ __launch_bounds__(256) __attribute__((amdgpu_waves_per_eu(2, 2)))
void vq_main(const float* __restrict__ x,
             const char* __restrict__ e16,
             const float* __restrict__ se25,
             u32* __restrict__ cand) {
  __shared__ __align__(16) char Abuf[32768];   // fragment-linear A (64 rows x 256 k), scratch aliased after loop

  const int tid = threadIdx.x;
  const int lane = tid & 63;
  const int wn = tid >> 6;              // 0..3 col-strip wave
  const int l15 = lane & 15;
  const int lg  = lane >> 4;            // 0..3
  const int split = blockIdx.x & 3;
  const int bm = (blockIdx.x >> 2) * BMr;
  const int nbase = split * NRANGE;

  int aOff[4];
#pragma unroll
  for (int mi = 0; mi < 4; ++mi) aOff[mi] = mi * 8192 + lg * 256 + l15 * 16;

  // ---- stage A ONCE: convert x (*2^9) to f16, fragment-linear 64x256 panel ----
  {
    const int row = tid >> 2, seg = tid & 3;    // 64 rows x 4 segments of 64 floats
    const float4* xs = (const float4*)(x + (size_t)(bm + row) * EDIM + seg * 64);
    const int ab = (row >> 4) * 8192 + (row & 15) * 16;
#pragma unroll
    for (int u = 0; u < 8; ++u) {
      float4 a0 = xs[2 * u], a1 = xs[2 * u + 1];
      f16x8 hv;
      hv[0] = (f16)(a0.x * XSCALE); hv[1] = (f16)(a0.y * XSCALE);
      hv[2] = (f16)(a0.z * XSCALE); hv[3] = (f16)(a0.w * XSCALE);
      hv[4] = (f16)(a1.x * XSCALE); hv[5] = (f16)(a1.y * XSCALE);
      hv[6] = (f16)(a1.z * XSCALE); hv[7] = (f16)(a1.w * XSCALE);
      *(f16x8*)&Abuf[ab + (seg * 8 + u) * 256] = hv;
    }
  }
  __syncthreads();   // A visible to all waves; only barrier before the merge

  // per-lane B base: colblock (split*128 + wn*4), kslice sub-offset lg*256, col l15*16
  const char* ebase = e16 + (size_t)(split * 128 + wn * 4) * 8192 + lg * 256 + l15 * 16;

  f16x8 bvA[4], bvB[4];
#pragma unroll
  for (int ni = 0; ni < 4; ++ni)
    bvA[ni] = *(const f16x8*)(ebase + (size_t)ni * 8192);   // prefetch chunk 0 (t=0,q=0)

  u32 d1[16], d2[16], d3[16], d4[16];
#pragma unroll
  for (int s = 0; s < 16; ++s) { d1[s] = 0u; d2[s] = 0u; d3[s] = 0u; d4[s] = 0u; }

  const int idl = wn * 64 + l15;   // lane part of the candidate id

  for (int t = 0; t < 8; ++t) {
    float sev[4];
#pragma unroll
    for (int ni = 0; ni < 4; ++ni)
      sev[ni] = se25[nbase + t * 256 + wn * 64 + ni * 16 + l15];

    f32x4 acc[4][4];
#pragma unroll
    for (int mi = 0; mi < 4; ++mi)
#pragma unroll
      for (int ni = 0; ni < 4; ++ni)
        acc[mi][ni] = (f32x4){OFFSETF, OFFSETF, OFFSETF, OFFSETF};

#pragma unroll
    for (int q = 0; q < 8; ++q) {
      const int c1 = (t * 8 + q + 1) & 63;     // next chunk (wrap: harmless re-load)
      const int ntt = c1 >> 3, nq = c1 & 7;
      const char* src = ebase + (size_t)(ntt * 16) * 8192 + nq * 1024;
      f16x8 av[4];
#pragma unroll
      for (int mi = 0; mi < 4; ++mi) av[mi] = *(const f16x8*)&Abuf[aOff[mi] + q * 1024];
      if ((q & 1) == 0) {
#pragma unroll
        for (int ni = 0; ni < 4; ++ni) bvB[ni] = *(const f16x8*)(src + (size_t)ni * 8192);
        __builtin_amdgcn_s_setprio(1);
#pragma unroll
        for (int mi = 0; mi < 4; ++mi)
#pragma unroll
          for (int ni = 0; ni < 4; ++ni)
            acc[mi][ni] = __builtin_amdgcn_mfma_f32_16x16x32_f16(av[mi], bvA[ni], acc[mi][ni], 0, 0, 0);
        __builtin_amdgcn_s_setprio(0);
      } else {
#pragma unroll
        for (int ni = 0; ni < 4; ++ni) bvA[ni] = *(const f16x8*)(src + (size_t)ni * 8192);
        __builtin_amdgcn_s_setprio(1);
#pragma unroll
        for (int mi = 0; mi < 4; ++mi)
#pragma unroll
          for (int ni = 0; ni < 4; ++ni)
            acc[mi][ni] = __builtin_amdgcn_mfma_f32_16x16x32_f16(av[mi], bvB[ni], acc[mi][ni], 0, 0, 0);
        __builtin_amdgcn_s_setprio(0);
      }
    }

    // ---- per-tile epilogue: pack (low 11 bits = split-local col) + top-4 ----
#pragma unroll
    for (int ni = 0; ni < 4; ++ni) {
      const u32 id = (u32)(t * 256 + ni * 16 + idl);
#pragma unroll
      for (int mi = 0; mi < 4; ++mi)
#pragma unroll
        for (int r = 0; r < 4; ++r) {
          u32 up = (__float_as_uint(acc[mi][ni][r] + sev[ni]) & 0xFFFFF800u) | id;
          int s = mi * 4 + r;
          ins4max(up, d1[s], d2[s], d3[s], d4[s]);
        }
    }
  }

  // ---- intra-wave 16-lane butterfly merge ----
#pragma unroll
  for (int off = 8; off >= 1; off >>= 1) {
#pragma unroll
    for (int s = 0; s < 16; ++s) {
      u32 e1 = (u32)__shfl_xor((int)d1[s], off);
      u32 e2 = (u32)__shfl_xor((int)d2[s], off);
      u32 e3 = (u32)__shfl_xor((int)d3[s], off);
      u32 e4 = (u32)__shfl_xor((int)d4[s], off);
      ins4max(e1, d1[s], d2[s], d3[s], d4[s]);
      ins4max(e2, d1[s], d2[s], d3[s], d4[s]);
      ins4max(e3, d1[s], d2[s], d3[s], d4[s]);
      ins4max(e4, d1[s], d2[s], d3[s], d4[s]);
    }
  }
  __syncthreads();   // A dead -> alias merge scratch
  u32 (*scratch)[4][16][4] = (u32 (*)[4][16][4])Abuf;   // 4 waves x 4 lg x 16 s x 4 = 4 KB
  if (l15 == 0) {
#pragma unroll
    for (int s = 0; s < 16; ++s) {
      scratch[wn][lg][s][0] = d1[s];
      scratch[wn][lg][s][1] = d2[s];
      scratch[wn][lg][s][2] = d3[s];
      scratch[wn][lg][s][3] = d4[s];
    }
  }
  __syncthreads();
  // ---- cross-wave merge over the 4 wn waves; write per-split top-4 (best first) ----
  if (tid < 64) {
    const int row = tid;
    const int mi = row >> 4, lgr = (row >> 2) & 3, rr = row & 3;
    const int s = mi * 4 + rr;
    u32 a1 = scratch[0][lgr][s][0];
    u32 a2 = scratch[0][lgr][s][1];
    u32 a3 = scratch[0][lgr][s][2];
    u32 a4 = scratch[0][lgr][s][3];
#pragma unroll
    for (int w = 1; w < 4; ++w) {
#pragma unroll
      for (int c = 0; c < 4; ++c)
        ins4max(scratch[w][lgr][s][c], a1, a2, a3, a4);
    }
    size_t base = (size_t)split * (N_TOK * 4) + (size_t)(bm + row) * 4;
    cand[base + 0] = a1; cand[base + 1] = a2; cand[base + 2] = a3; cand[base + 3] = a4;
  }
}

// ---------------- gather: wave-per-token (4/block); margin select + guard + exact refine + output ----------------
__global__ __launch_bounds__(256) void vq_gather_kernel(
    const float* __restrict__ x, const float* __restrict__ emb,
    const float* __restrict__ sx, const float* __restrict__ se,
    const u32* __restrict__ cand,
    float* __restrict__ out_q, float* __restrict__ out_idx,
    float* __restrict__ partials,
    u32* __restrict__ rcnt, u32* __restrict__ rlist, u64* __restrict__ rbest) {
  const int wid = threadIdx.x >> 6;
  const int lane = threadIdx.x & 63;
  const int token = blockIdx.x * 4 + wid;
  __shared__ int s_cj[4][16];

  // lanes 0..15 load the 16 candidates (sp = lane>>2, c = lane&3)
  const int sp = lane >> 2, cc = lane & 3;
  u32 v = 0u;
  float f = FLT_MAX;
  if (lane < 16) {
    v = cand[(size_t)sp * (N_TOK * 4) + (size_t)token * 4 + cc];
    f = __uint_as_float(v);   // all stored scores are negative floats
  }
  float gmin = f;
#pragma unroll
  for (int off = 8; off >= 1; off >>= 1) gmin = fminf(gmin, __shfl_xor(gmin, off, 16));
  gmin = __shfl(gmin, 0);

  const bool inm = (lane < 16) && (f <= gmin + MARGIN_F);
  const u64 mb = __ballot(inm);
  // guard: any split's stored 4th-best (c==3 lanes: bits 3,7,11,15) within margin
  if (mb & 0x8888ull) {
    if (lane == 0) {
      u32 slot = atomicAdd(rcnt, 1u);
      rlist[slot] = (u32)token;
      rbest[slot] = ~0ull;
    }
    return;   // token handled by rescan kernels (whole wave exits; no block barriers used)
  }
  const int cnt = __popcll(mb);
  if (inm) {
    int pos = __popcll(mb & ((1ull << lane) - 1ull));
    s_cj[wid][pos] = sp * NRANGE + (int)(v & 0x7FFu);   // id == split-local col
  }
  asm volatile("s_waitcnt lgkmcnt(0)" ::: "memory");   // own-wave LDS writes visible

  int j;
  if (cnt == 1) {
    j = s_cj[wid][0];
  } else {
    float dv = FLT_MAX;
    int jv = 0x7FFFFFFF;
    if (lane < cnt) {
      jv = s_cj[wid][lane];
      const float* xr = x + (size_t)token * EDIM;
      const float* er = emb + (size_t)jv * EDIM;
      float a = 0.f;
      for (int k = 0; k < EDIM; ++k) a = fmaf(xr[k], er[k], a);   // exact reference chain
      dv = (sx[token] + se[jv]) - 2.0f * a;                        // exact reference epilogue
    }
#pragma unroll
    for (int off = 8; off >= 1; off >>= 1) {
      float d2 = __shfl_xor(dv, off, 16);
      int   j2 = __shfl_xor(jv, off, 16);
      if (d2 < dv || (d2 == dv && j2 < jv)) { dv = d2; jv = j2; }
    }
    j = __shfl(jv, 0);
  }

  if (lane == 0) out_idx[token] = (float)j;
  const float4 xv = *(const float4*)(x + (size_t)token * EDIM + lane * 4);
  const float4 qv = *(const float4*)(emb + (size_t)j * EDIM + lane * 4);
  float4 df, o;
  df.x = qv.x - xv.x; df.y = qv.y - xv.y; df.z = qv.z - xv.z; df.w = qv.w - xv.w;
  o.x = xv.x + df.x; o.y = xv.y + df.y; o.z = xv.z + df.z; o.w = xv.w + df.w;
  *(float4*)(out_q + (size_t)token * EDIM + lane * 4) = o;
  float sq = (df.x * df.x + df.y * df.y) + (df.z * df.z + df.w * df.w);
#pragma unroll
  for (int off = 32; off >= 1; off >>= 1) sq += __shfl_xor(sq, off);
  if (lane == 0) partials[token] = sq;
}

// ---------------- rescan phase A: parallel exact scan, work-item = (token, 256-row chunk) ----------------
__global__ __launch_bounds__(256) void vq_rescan_scan(
    const float* __restrict__ x, const float* __restrict__ emb,
    const float* __restrict__ sx, const float* __restrict__ se,
    const u32* __restrict__ rcnt, const u32* __restrict__ rlist,
    u64* __restrict__ rbest) {
  const int tid = threadIdx.x;
  const int n = (int)rcnt[0];
  const int total = n * 32;
  __shared__ float xs[EDIM];
  __shared__ u64 rw[4];

  for (int w = blockIdx.x; w < total; w += gridDim.x) {
    const int it = w >> 5, chunk = w & 31;
    const int token = (int)rlist[it];
    __syncthreads();
    xs[tid] = x[(size_t)token * EDIM + tid];
    __syncthreads();
    const float sxt = sx[token];
    const int j = chunk * 256 + tid;
    const float* er = emb + (size_t)j * EDIM;
    float a = 0.f;
#pragma unroll 8
    for (int k4 = 0; k4 < 64; ++k4) {
      float4 e4 = ((const float4*)er)[k4];
      float4 x4 = ((const float4*)xs)[k4];
      a = fmaf(x4.x, e4.x, a);
      a = fmaf(x4.y, e4.y, a);
      a = fmaf(x4.z, e4.z, a);
      a = fmaf(x4.w, e4.w, a);
    }
    float d = (sxt + se[j]) - 2.0f * a;
    u64 pk = ((u64)__float_as_uint(d) << 32) | (u32)j;
    const int lane = tid & 63, wave = tid >> 6;
#pragma unroll
    for (int off = 32; off >= 1; off >>= 1) {
      u64 o = __shfl_xor(pk, off);
      pk = o < pk ? o : pk;
    }
    if (lane == 0) rw[wave] = pk;
    __syncthreads();
    if (tid == 0) {
      u64 b = rw[0];
#pragma unroll
      for (int ww = 1; ww < 4; ++ww) b = rw[ww] < b ? rw[ww] : b;
      atomicMin(rbest + it, b);
    }
  }
}

// ---------------- rescan phase B: write outputs for guarded tokens ----------------
__global__ __launch_bounds__(256) void vq_rescan_write(
    const float* __restrict__ x, const float* __restrict__ emb,
    const u32* __restrict__ rcnt, const u32* __restrict__ rlist,
    const u64* __restrict__ rbest,
    float* __restrict__ out_q, float* __restrict__ out_idx,
    float* __restrict__ partials) {
  const int tid = threadIdx.x;
  const int n = (int)rcnt[0];
  __shared__ float red[4];

  for (int it = blockIdx.x; it < n; it += gridDim.x) {
    const int token = (int)rlist[it];
    const int j = (int)(u32)(rbest[it] & 0xFFFFFFFFull);
    if (tid == 0) out_idx[token] = (float)j;
    float xv = x[(size_t)token * EDIM + tid];
    float q  = emb[(size_t)j * EDIM + tid];
    float diff = q - xv;
    out_q[(size_t)token * EDIM + tid] = xv + diff;
    float sq = diff * diff;
#pragma unroll
    for (int off = 32; off >= 1; off >>= 1) sq += __shfl_xor(sq, off);
    const int lane = tid & 63, wave = tid >> 6;
    __syncthreads();
    if (lane == 0) red[wave] = sq;
    __syncthreads();
    if (tid == 0) partials[token] = (red[0] + red[1]) + (red[2] + red[3]);
  }
}

// ---------------- final loss reduction ----------------
__global__ __launch_bounds__(256) void vq_loss_kernel(const float* __restrict__ partials,
                                                      float* __restrict__ loss_out) {
  const int tid = threadIdx.x;
  float s = 0.f;
  for (int i = tid; i < N_TOK; i += 256) s += partials[i];
  __shared__ float red[4];
#pragma unroll
  for (int off = 32; off >= 1; off >>= 1) s += __shfl_xor(s, off);
  const int wave = tid >> 6, lane = tid & 63;
  if (lane == 0) red[wave] = s;
  __syncthreads();
  if (tid == 0) {
    float tot = (red[0] + red[1]) + (red[2] + red[3]);
    float mean = tot / (float)(N_TOK * EDIM);
    loss_out[0] = mean + MU_W * mean;
  }
}

extern "C" void kernel_launch(void* const* d_in, const int* in_sizes, int n_in,
                              void* d_out, int out_size, void* d_ws, size_t ws_size,
                              hipStream_t stream) {
  const float* x   = (const float*)d_in[0];
  const float* emb = (const float*)d_in[1];

  float* out      = (float*)d_out;
  float* out_q    = out;
  float* out_loss = out + (size_t)N_TOK * EDIM;
  float* out_idx  = out_loss + 1;

  char* w = (char*)d_ws;
  char*  emb16    = w + WS_EMB16;
  float* sx       = (float*)(w + WS_SX);
  float* se       = (float*)(w + WS_SE);
  float* se25     = (float*)(w + WS_SE25);
  u32*   cand     = (u32*)(w + WS_CAND);
  float* partials = (float*)(w + WS_PART);
  u32*   rcnt     = (u32*)(w + WS_RCNT);
  u32*   rlist    = (u32*)(w + WS_RLIST);
  u64*   rbest    = (u64*)(w + WS_RBEST);

  conv_fused<<<(N_E + N_TOK) / 4, 256, 0, stream>>>(emb, x, emb16, se, se25, sx, rcnt);

  vq_main<<<NSPLIT * (N_TOK / BMr), 256, 0, stream>>>(x, emb16, se25, cand);

  vq_gather_kernel<<<N_TOK / 4, 256, 0, stream>>>(x, emb, sx, se, cand, out_q, out_idx, partials,
                                                  rcnt, rlist, rbest);
  vq_rescan_scan<<<2048, 256, 0, stream>>>(x, emb, sx, se, rcnt, rlist, rbest);
  vq_rescan_write<<<64, 256, 0, stream>>>(x, emb, rcnt, rlist, rbest, out_q, out_idx, partials);
  vq_loss_kernel<<<1, 256, 0, stream>>>(partials, out_loss);
}

// Round 16
// 285.767 us; speedup vs baseline: 1.5797x; 1.5797x over previous
//
#include <hip/hip_runtime.h>
#include <float.h>
#include <stdint.h>

#define N_TOK 32768
#define N_E   8192
#define EDIM  256
#define MU_W  0.25f
#define NSPLIT 4
#define NRANGE 2048
#define BMr 64                /* block rows (tokens) */
#define MARGIN_F 4096.0f      /* scaled units (2^25): 1.2e-4 d >= ref-ulp + 2*quantum + 8-sigma noise */
#define OFFSETF (-0x1p21f)    /* folded into se25b: makes every score negative -> raw-bit u32 max-ordering */
#define XSCALE 512.0f         /* 2^9 */
#define ESCALE -131072.0f     /* -2^17 ; product sums to -dot*2^26 = -2dot*2^25 */

typedef _Float16 f16;
typedef _Float16 f16x8 __attribute__((ext_vector_type(8)));
typedef _Float16 f16x4 __attribute__((ext_vector_type(4)));
typedef float f32x4 __attribute__((ext_vector_type(4)));
typedef unsigned int u32;
typedef unsigned long long u64;

// ws layout (bytes)
#define WS_EMB16   0
#define WS_SX      4194304
#define WS_SE      4325376
#define WS_SE25    4358144
#define WS_CAND    4390912
#define WS_PART    6488064
#define WS_RCNT    6619136
#define WS_RLIST   6619392
#define WS_RBEST   6750464   /* 32768 x u64 */

__device__ inline void gload_lds16(const void* g, void* l) {
  __builtin_amdgcn_global_load_lds(
      (const __attribute__((address_space(1))) unsigned int*)g,
      (__attribute__((address_space(3))) unsigned int*)l, 16, 0, 0);
}

__device__ inline u32 umax_(u32 a, u32 b) { return a > b ? a : b; }
__device__ inline u32 umin_(u32 a, u32 b) { return a < b ? a : b; }

__device__ inline u32 med3u(u32 a, u32 b, u32 c) {
  u32 r;
  asm("v_med3_u32 %0, %1, %2, %3" : "=v"(r) : "v"(a), "v"(b), "v"(c));
  return r;
}

// sorted top-4 insert, DESCENDING u32 (a>=b>=c>=d; larger u32 = more-negative float = better)
__device__ inline void ins4max(u32 v, u32& a, u32& b, u32& c, u32& d) {
  u32 na = umax_(a, v);
  u32 nb = med3u(a, b, v);
  u32 nc = med3u(b, c, v);
  u32 nd = med3u(c, d, v);
  a = na; b = nb; c = nc; d = nd;
}

// ---------------- fused prepass: rownorms (exact tree) + fragment-linear scaled f16 + (se*2^25+OFFSET) + rcnt=0 ----------------
// e16 layout: [colblock=j>>4][kslice=k>>3][col16=j&15] x 16B  (8192 B per 16-col block)
__global__ __launch_bounds__(256) void conv_fused(const float* __restrict__ emb,
                                                  const float* __restrict__ x,
                                                  char* __restrict__ dst16,
                                                  float* __restrict__ se,
                                                  float* __restrict__ se25,
                                                  float* __restrict__ sx,
                                                  u32* __restrict__ rcnt) {
  if (blockIdx.x == 0 && threadIdx.x == 0) rcnt[0] = 0u;
  int wave = threadIdx.x >> 6;
  int lane = threadIdx.x & 63;
  int row = blockIdx.x * 4 + wave;
  if (row < N_E) {
    const float4 v = *(const float4*)(emb + (size_t)row * EDIM + lane * 4);
    float s = (v.x * v.x + v.y * v.y) + (v.z * v.z + v.w * v.w);
#pragma unroll
    for (int off = 32; off >= 1; off >>= 1) s += __shfl_xor(s, off);
    if (lane == 0) {
      se[row] = s;
      se25[row] = s * 0x1p25f + OFFSETF;   // rounding <= 0.25 scaled units (<< MARGIN slop)
    }
    f16x4 h;
    h[0] = (f16)(v.x * ESCALE); h[1] = (f16)(v.y * ESCALE);
    h[2] = (f16)(v.z * ESCALE); h[3] = (f16)(v.w * ESCALE);
    *(f16x4*)(dst16 + (size_t)(row >> 4) * 8192 + (lane >> 1) * 256 +
              (row & 15) * 16 + (lane & 1) * 8) = h;
  } else {
    int xr = row - N_E;
    const float4 v = *(const float4*)(x + (size_t)xr * EDIM + lane * 4);
    float s = (v.x * v.x + v.y * v.y) + (v.z * v.z + v.w * v.w);
#pragma unroll
    for (int off = 32; off >= 1; off >>= 1) s += __shfl_xor(s, off);
    if (lane == 0) sx[xr] = s;
  }
}

// ---------------- stage-1 (R10 structure): fp16 MFMA GEMM, 64-row tile, triple-buffered B, 2 blocks/CU ----------------
// grid 2048: split = bid&3, bm = (bid>>2)*64. 256 threads = 4 waves (wn), wave tile 64x64.
// se+OFFSET folded into acc init (R7-validated pattern) -> epilogue = 1 fused pack + 4 sort ops per candidate.
__global__ __launch_bounds__(256, 2) void vq_main(const float* __restrict__ x,
                                                  const char* __restrict__ e16,
                                                  const float* __restrict__ se25,
                                                  u32* __restrict__ cand) {
  __shared__ __align__(16) char lds[81920];   // 32 KB A + 3 x 16 KB B (scratch aliased in A after loop)
  char* Abuf = lds;
  char* Bbuf = lds + 32768;

  const int tid = threadIdx.x;          // 0..255
  const int lane = tid & 63;
  const int wn = tid >> 6;              // 0..3 col-group wave
  const int l15 = lane & 15;
  const int lg  = lane >> 4;            // 0..3
  const int split = blockIdx.x & 3;
  const int bm = (blockIdx.x >> 2) * BMr;
  const int nbase = split * NRANGE;
  const int splitRB = split * 128;      // rowblock base of this split in e16

  // per-thread fragment base byte-offsets (lane-const)
  int aOff[4], bOff[4];
#pragma unroll
  for (int mi = 0; mi < 4; ++mi) aOff[mi] = mi * 8192 + lg * 256 + l15 * 16;
#pragma unroll
  for (int ni = 0; ni < 4; ++ni) bOff[ni] = (wn * 4 + ni) * 1024 + lg * 256 + l15 * 16;

  // B chunk stage: 1024 16B-units, 4 per thread
  int svo[4], sdo[4];
#pragma unroll
  for (int l = 0; l < 4; ++l) {
    int u = l * 256 + tid;
    svo[l] = (u >> 6) * 8192 + (u & 63) * 16;   // + (splitRB + t*16)*8192 + q*1024
    sdo[l] = (u >> 6) * 1024 + (u & 63) * 16;   // + buf*16384
  }

  // ---- stage A ONCE: convert x (*2^9) to f16, fragment-linear 64x256 panel ----
  {
    const int row = tid >> 2, seg = tid & 3;    // 64 rows x 4 segments of 64 floats
    const float4* xs = (const float4*)(x + (size_t)(bm + row) * EDIM + seg * 64);
    const int ab = (row >> 4) * 8192 + (row & 15) * 16;
#pragma unroll
    for (int u = 0; u < 8; ++u) {
      float4 a0 = xs[2 * u], a1 = xs[2 * u + 1];
      f16x8 hv;
      hv[0] = (f16)(a0.x * XSCALE); hv[1] = (f16)(a0.y * XSCALE);
      hv[2] = (f16)(a0.z * XSCALE); hv[3] = (f16)(a0.w * XSCALE);
      hv[4] = (f16)(a1.x * XSCALE); hv[5] = (f16)(a1.y * XSCALE);
      hv[6] = (f16)(a1.z * XSCALE); hv[7] = (f16)(a1.w * XSCALE);
      *(f16x8*)&Abuf[ab + (seg * 8 + u) * 256] = hv;
    }
  }
  // ---- stage B chunk 0 into buf 0 ----
  {
    const size_t eb = (size_t)splitRB * 8192;
#pragma unroll
    for (int l = 0; l < 4; ++l) gload_lds16(e16 + eb + svo[l], Bbuf + sdo[l]);
  }
  __syncthreads();   // A visible; chunk-0 landed; vmcnt ledger = 0

  u32 d1[16], d2[16], d3[16], d4[16];
#pragma unroll
  for (int s = 0; s < 16; ++s) { d1[s] = 0u; d2[s] = 0u; d3[s] = 0u; d4[s] = 0u; }

  const int idl = wn * 64 + l15;   // lane part of the candidate id

  int bufc = 0;                    // buffer of current chunk (c mod 3)
  for (int t = 0; t < 8; ++t) {
    float sev[4];
#pragma unroll
    for (int ni = 0; ni < 4; ++ni)
      sev[ni] = se25[nbase + t * 256 + wn * 64 + ni * 16 + l15];

    f32x4 acc[4][4];
#pragma unroll
    for (int mi = 0; mi < 4; ++mi)
#pragma unroll
      for (int ni = 0; ni < 4; ++ni)
        acc[mi][ni] = (f32x4){sev[ni], sev[ni], sev[ni], sev[ni]};   // se*2^25 + OFFSET preloaded

#pragma unroll
    for (int q = 0; q < 8; ++q) {
      const int c = t * 8 + q;
      const int cn = (c + 1) & 63;             // wrap: harmless re-stage of chunk 0
      const int tn = cn >> 3, qn = cn & 7;
      const int bufn = (bufc == 2) ? 0 : bufc + 1;
      // ---- issue next-chunk stage into buf (c+1)%3 (race-free: its readers ended 2 barriers ago) ----
      {
        const size_t ebN = (size_t)(splitRB + tn * 16) * 8192 + qn * 1024;
        char* dstN = Bbuf + bufn * 16384;
#pragma unroll
        for (int l = 0; l < 4; ++l) gload_lds16(e16 + ebN + svo[l], dstN + sdo[l]);
      }
      asm volatile("s_waitcnt vmcnt(4)" ::: "memory");   // drain own chunk-c loads, keep next in flight
      __builtin_amdgcn_s_barrier();                      // all waves' chunk-c stores landed
      __builtin_amdgcn_sched_barrier(0);
      {
        const char* Bc = Bbuf + bufc * 16384;
        f16x8 av[4], bv[4];
#pragma unroll
        for (int mi = 0; mi < 4; ++mi) av[mi] = *(const f16x8*)&Abuf[aOff[mi] + q * 1024];
#pragma unroll
        for (int ni = 0; ni < 4; ++ni) bv[ni] = *(const f16x8*)&Bc[bOff[ni]];
        __builtin_amdgcn_s_setprio(1);
#pragma unroll
        for (int mi = 0; mi < 4; ++mi)
#pragma unroll
          for (int ni = 0; ni < 4; ++ni)
            acc[mi][ni] = __builtin_amdgcn_mfma_f32_16x16x32_f16(av[mi], bv[ni], acc[mi][ni], 0, 0, 0);
        __builtin_amdgcn_s_setprio(0);
      }
      bufc = bufn;
    }

    // ---- per-tile epilogue: fused pack (v_and_or) + top-4 ----
#pragma unroll
    for (int ni = 0; ni < 4; ++ni) {
      const u32 id = (u32)(t * 256 + ni * 16 + idl);
#pragma unroll
      for (int mi = 0; mi < 4; ++mi)
#pragma unroll
        for (int r = 0; r < 4; ++r) {
          u32 up = (__float_as_uint(acc[mi][ni][r]) & 0xFFFFF800u) | id;
          int s = mi * 4 + r;
          ins4max(up, d1[s], d2[s], d3[s], d4[s]);
        }
    }
  }

  __syncthreads();   // full drain (incl. wrap stage); Abuf dead -> alias scratch

  // ---- intra-wave 16-lane butterfly merge ----
#pragma unroll
  for (int off = 8; off >= 1; off >>= 1) {
#pragma unroll
    for (int s = 0; s < 16; ++s) {
      u32 e1 = (u32)__shfl_xor((int)d1[s], off);
      u32 e2 = (u32)__shfl_xor((int)d2[s], off);
      u32 e3 = (u32)__shfl_xor((int)d3[s], off);
      u32 e4 = (u32)__shfl_xor((int)d4[s], off);
      ins4max(e1, d1[s], d2[s], d3[s], d4[s]);
      ins4max(e2, d1[s], d2[s], d3[s], d4[s]);
      ins4max(e3, d1[s], d2[s], d3[s], d4[s]);
      ins4max(e4, d1[s], d2[s], d3[s], d4[s]);
    }
  }
  u32 (*scratch)[4][16][4] = (u32 (*)[4][16][4])lds;   // 4 waves x 4 lg x 16 s x 4 = 4 KB (aliases Abuf)
  if (l15 == 0) {
#pragma unroll
    for (int s = 0; s < 16; ++s) {
      scratch[wn][lg][s][0] = d1[s];
      scratch[wn][lg][s][1] = d2[s];
      scratch[wn][lg][s][2] = d3[s];
      scratch[wn][lg][s][3] = d4[s];
    }
  }
  __syncthreads();
  // ---- cross-wave merge over the 4 wn waves; write per-split top-4 (best first) ----
  if (tid < 64) {
    const int row = tid;
    const int mi = row >> 4, lgr = (row >> 2) & 3, rr = row & 3;
    const int s = mi * 4 + rr;
    u32 a1 = scratch[0][lgr][s][0];
    u32 a2 = scratch[0][lgr][s][1];
    u32 a3 = scratch[0][lgr][s][2];
    u32 a4 = scratch[0][lgr][s][3];
#pragma unroll
    for (int w = 1; w < 4; ++w) {
#pragma unroll
      for (int c = 0; c < 4; ++c)
        ins4max(scratch[w][lgr][s][c], a1, a2, a3, a4);
    }
    size_t base = (size_t)split * (N_TOK * 4) + (size_t)(bm + row) * 4;
    cand[base + 0] = a1; cand[base + 1] = a2; cand[base + 2] = a3; cand[base + 3] = a4;
  }
}

// ---------------- gather: wave-per-token (4/block); margin select + guard + exact refine + output ----------------
__global__ __launch_bounds__(256) void vq_gather_kernel(
    const float* __restrict__ x, const float* __restrict__ emb,
    const float* __restrict__ sx, const float* __restrict__ se,
    const u32* __restrict__ cand,
    float* __restrict__ out_q, float* __restrict__ out_idx,
    float* __restrict__ partials,
    u32* __restrict__ rcnt, u32* __restrict__ rlist, u64* __restrict__ rbest) {
  const int wid = threadIdx.x >> 6;
  const int lane = threadIdx.x & 63;
  const int token = blockIdx.x * 4 + wid;
  __shared__ int s_cj[4][16];

  // lanes 0..15 load the 16 candidates (sp = lane>>2, c = lane&3)
  const int sp = lane >> 2, cc = lane & 3;
  u32 v = 0u;
  float f = FLT_MAX;
  if (lane < 16) {
    v = cand[(size_t)sp * (N_TOK * 4) + (size_t)token * 4 + cc];
    f = __uint_as_float(v);   // all stored scores are negative floats
  }
  float gmin = f;
#pragma unroll
  for (int off = 8; off >= 1; off >>= 1) gmin = fminf(gmin, __shfl_xor(gmin, off, 16));
  gmin = __shfl(gmin, 0);

  const bool inm = (lane < 16) && (f <= gmin + MARGIN_F);
  const u64 mb = __ballot(inm);
  // guard: any split's stored 4th-best (c==3 lanes: bits 3,7,11,15) within margin
  if (mb & 0x8888ull) {
    if (lane == 0) {
      u32 slot = atomicAdd(rcnt, 1u);
      rlist[slot] = (u32)token;
      rbest[slot] = ~0ull;
    }
    return;   // token handled by rescan kernels (whole wave exits; no block barriers used)
  }
  const int cnt = __popcll(mb);
  if (inm) {
    int pos = __popcll(mb & ((1ull << lane) - 1ull));
    s_cj[wid][pos] = sp * NRANGE + (int)(v & 0x7FFu);   // id == split-local col
  }
  asm volatile("s_waitcnt lgkmcnt(0)" ::: "memory");   // own-wave LDS writes visible

  int j;
  if (cnt == 1) {
    j = s_cj[wid][0];
  } else {
    float dv = FLT_MAX;
    int jv = 0x7FFFFFFF;
    if (lane < cnt) {
      jv = s_cj[wid][lane];
      const float* xr = x + (size_t)token * EDIM;
      const float* er = emb + (size_t)jv * EDIM;
      float a = 0.f;
      for (int k = 0; k < EDIM; ++k) a = fmaf(xr[k], er[k], a);   // exact reference chain
      dv = (sx[token] + se[jv]) - 2.0f * a;                        // exact reference epilogue
    }
#pragma unroll
    for (int off = 8; off >= 1; off >>= 1) {
      float d2 = __shfl_xor(dv, off, 16);
      int   j2 = __shfl_xor(jv, off, 16);
      if (d2 < dv || (d2 == dv && j2 < jv)) { dv = d2; jv = j2; }
    }
    j = __shfl(jv, 0);
  }

  if (lane == 0) out_idx[token] = (float)j;
  const float4 xv = *(const float4*)(x + (size_t)token * EDIM + lane * 4);
  const float4 qv = *(const float4*)(emb + (size_t)j * EDIM + lane * 4);
  float4 df, o;
  df.x = qv.x - xv.x; df.y = qv.y - xv.y; df.z = qv.z - xv.z; df.w = qv.w - xv.w;
  o.x = xv.x + df.x; o.y = xv.y + df.y; o.z = xv.z + df.z; o.w = xv.w + df.w;
  *(float4*)(out_q + (size_t)token * EDIM + lane * 4) = o;
  float sq = (df.x * df.x + df.y * df.y) + (df.z * df.z + df.w * df.w);
#pragma unroll
  for (int off = 32; off >= 1; off >>= 1) sq += __shfl_xor(sq, off);
  if (lane == 0) partials[token] = sq;
}

// ---------------- rescan phase A: parallel exact scan, work-item = (token, 256-row chunk) ----------------
__global__ __launch_bounds__(256) void vq_rescan_scan(
    const float* __restrict__ x, const float* __restrict__ emb,
    const float* __restrict__ sx, const float* __restrict__ se,
    const u32* __restrict__ rcnt, const u32* __restrict__ rlist,
    u64* __restrict__ rbest) {
  const int tid = threadIdx.x;
  const int n = (int)rcnt[0];
  const int total = n * 32;
  __shared__ float xs[EDIM];
  __shared__ u64 rw[4];

  for (int w = blockIdx.x; w < total; w += gridDim.x) {
    const int it = w >> 5, chunk = w & 31;
    const int token = (int)rlist[it];
    __syncthreads();
    xs[tid] = x[(size_t)token * EDIM + tid];
    __syncthreads();
    const float sxt = sx[token];
    const int j = chunk * 256 + tid;
    const float* er = emb + (size_t)j * EDIM;
    float a = 0.f;
#pragma unroll 8
    for (int k4 = 0; k4 < 64; ++k4) {
      float4 e4 = ((const float4*)er)[k4];
      float4 x4 = ((const float4*)xs)[k4];
      a = fmaf(x4.x, e4.x, a);
      a = fmaf(x4.y, e4.y, a);
      a = fmaf(x4.z, e4.z, a);
      a = fmaf(x4.w, e4.w, a);
    }
    float d = (sxt + se[j]) - 2.0f * a;
    u64 pk = ((u64)__float_as_uint(d) << 32) | (u32)j;
    const int lane = tid & 63, wave = tid >> 6;
#pragma unroll
    for (int off = 32; off >= 1; off >>= 1) {
      u64 o = __shfl_xor(pk, off);
      pk = o < pk ? o : pk;
    }
    if (lane == 0) rw[wave] = pk;
    __syncthreads();
    if (tid == 0) {
      u64 b = rw[0];
#pragma unroll
      for (int ww = 1; ww < 4; ++ww) b = rw[ww] < b ? rw[ww] : b;
      atomicMin(rbest + it, b);
    }
  }
}

// ---------------- rescan phase B: write outputs for guarded tokens ----------------
__global__ __launch_bounds__(256) void vq_rescan_write(
    const float* __restrict__ x, const float* __restrict__ emb,
    const u32* __restrict__ rcnt, const u32* __restrict__ rlist,
    const u64* __restrict__ rbest,
    float* __restrict__ out_q, float* __restrict__ out_idx,
    float* __restrict__ partials) {
  const int tid = threadIdx.x;
  const int n = (int)rcnt[0];
  __shared__ float red[4];

  for (int it = blockIdx.x; it < n; it += gridDim.x) {
    const int token = (int)rlist[it];
    const int j = (int)(u32)(rbest[it] & 0xFFFFFFFFull);
    if (tid == 0) out_idx[token] = (float)j;
    float xv = x[(size_t)token * EDIM + tid];
    float q  = emb[(size_t)j * EDIM + tid];
    float diff = q - xv;
    out_q[(size_t)token * EDIM + tid] = xv + diff;
    float sq = diff * diff;
#pragma unroll
    for (int off = 32; off >= 1; off >>= 1) sq += __shfl_xor(sq, off);
    const int lane = tid & 63, wave = tid >> 6;
    __syncthreads();
    if (lane == 0) red[wave] = sq;
    __syncthreads();
    if (tid == 0) partials[token] = (red[0] + red[1]) + (red[2] + red[3]);
  }
}

// ---------------- final loss reduction ----------------
__global__ __launch_bounds__(256) void vq_loss_kernel(const float* __restrict__ partials,
                                                      float* __restrict__ loss_out) {
  const int tid = threadIdx.x;
  float s = 0.f;
  for (int i = tid; i < N_TOK; i += 256) s += partials[i];
  __shared__ float red[4];
#pragma unroll
  for (int off = 32; off >= 1; off >>= 1) s += __shfl_xor(s, off);
  const int wave = tid >> 6, lane = tid & 63;
  if (lane == 0) red[wave] = s;
  __syncthreads();
  if (tid == 0) {
    float tot = (red[0] + red[1]) + (red[2] + red[3]);
    float mean = tot / (float)(N_TOK * EDIM);
    loss_out[0] = mean + MU_W * mean;
  }
}

extern "C" void kernel_launch(void* const* d_in, const int* in_sizes, int n_in,
                              void* d_out, int out_size, void* d_ws, size_t ws_size,
                              hipStream_t stream) {
  const float* x   = (const float*)d_in[0];
  const float* emb = (const float*)d_in[1];

  float* out      = (float*)d_out;
  float* out_q    = out;
  float* out_loss = out + (size_t)N_TOK * EDIM;
  float* out_idx  = out_loss + 1;

  char* w = (char*)d_ws;
  char*  emb16    = w + WS_EMB16;
  float* sx       = (float*)(w + WS_SX);
  float* se       = (float*)(w + WS_SE);
  float* se25     = (float*)(w + WS_SE25);
  u32*   cand     = (u32*)(w + WS_CAND);
  float* partials = (float*)(w + WS_PART);
  u32*   rcnt     = (u32*)(w + WS_RCNT);
  u32*   rlist    = (u32*)(w + WS_RLIST);
  u64*   rbest    = (u64*)(w + WS_RBEST);

  conv_fused<<<(N_E + N_TOK) / 4, 256, 0, stream>>>(emb, x, emb16, se, se25, sx, rcnt);

  vq_main<<<NSPLIT * (N_TOK / BMr), 256, 0, stream>>>(x, emb16, se25, cand);

  vq_gather_kernel<<<N_TOK / 4, 256, 0, stream>>>(x, emb, sx, se, cand, out_q, out_idx, partials,
                                                  rcnt, rlist, rbest);
  vq_rescan_scan<<<2048, 256, 0, stream>>>(x, emb, sx, se, rcnt, rlist, rbest);
  vq_rescan_write<<<64, 256, 0, stream>>>(x, emb, rcnt, rlist, rbest, out_q, out_idx, partials);
  vq_loss_kernel<<<1, 256, 0, stream>>>(partials, out_loss);
}